// Round 2
// baseline (849.301 us; speedup 1.0000x reference)
//
#include <hip/hip_runtime.h>

// ---------------- common types / helpers ----------------
typedef float v4f  __attribute__((ext_vector_type(4)));
typedef __bf16 bf16x8 __attribute__((ext_vector_type(8)));

__device__ __forceinline__ unsigned short f2bf(float f) {
    unsigned u = __builtin_bit_cast(unsigned, f);
    u += 0x7FFFu + ((u >> 16) & 1u);          // RNE
    return (unsigned short)(u >> 16);
}
__device__ __forceinline__ float bf2f(unsigned short h) {
    return __builtin_bit_cast(float, (unsigned)h << 16);
}

// async global->LDS DMA, 16B per lane. LDS dest must be wave-uniform base + lane*16.
__device__ __forceinline__ void gload16(const unsigned short* g, unsigned short* l) {
    __builtin_amdgcn_global_load_lds(
        (const __attribute__((address_space(1))) unsigned int*)g,
        (__attribute__((address_space(3))) unsigned int*)l, 16, 0, 0);
}

#define M_BATCH 16384

// ---------------- weight prep: fp32 [K,N] -> bf16 [N,Kpad] (transposed) ----------------
__global__ __launch_bounds__(256) void wprep(const float* __restrict__ in,
                                             unsigned short* __restrict__ out,
                                             int K, int N, int Kpad) {
    __shared__ float tile[32][33];
    int tx = threadIdx.x & 31;
    int ty = threadIdx.x >> 5;               // 0..7
    int n0 = blockIdx.x * 32, k0 = blockIdx.y * 32;
#pragma unroll
    for (int i = 0; i < 32; i += 8) {
        int k = k0 + ty + i, n = n0 + tx;
        tile[ty + i][tx] = (k < K && n < N) ? in[(size_t)k * N + n] : 0.f;
    }
    __syncthreads();
#pragma unroll
    for (int i = 0; i < 32; i += 8) {
        int n = n0 + ty + i, k = k0 + tx;
        if (n < N && k < Kpad) out[(size_t)n * Kpad + k] = f2bf(tile[tx][ty + i]);
    }
}

// ---------------- bottom layer 0: [B,13] @ [13,512] + b, relu -> bf16 ----------------
__global__ __launch_bounds__(256) void bot0(const float* __restrict__ x,
                                            const float* __restrict__ w,
                                            const float* __restrict__ b,
                                            unsigned short* __restrict__ h0) {
    int gid = blockIdx.x * 256 + threadIdx.x;          // M*512 threads
    int row = gid >> 9, col = gid & 511;
    const float* xr = x + (size_t)row * 39;
    float acc = b[col];
#pragma unroll
    for (int k = 0; k < 13; k++) acc += xr[k] * w[k * 512 + col];
    h0[gid] = f2bf(fmaxf(acc, 0.f));
}

// ---------------- generic bf16 MFMA GEMM: C = act(A[M,K] @ Bt[N,K]^T + bias) ----------------
// 128x128 tile, 4 waves, 4x4 16x16x32 acc per wave, BK=32.
// Staging via global_load_lds width=16 (m97 structure): LDS dest is linear in tid*16B,
// which satisfies the wave-uniform-base + lane*16 DMA constraint.
__global__ __launch_bounds__(256) void gemm_bt(const unsigned short* __restrict__ A,
                                               const unsigned short* __restrict__ Bt,
                                               const float* __restrict__ bias,
                                               unsigned short* __restrict__ C,
                                               int N, int K, int relu) {
    __shared__ __align__(16) unsigned short As[128 * 32];
    __shared__ __align__(16) unsigned short Bs[128 * 32];
    const int tid  = threadIdx.x;
    const int wave = tid >> 6, lane = tid & 63;
    const int quad = lane >> 4, r16 = lane & 15;
    const int m_blk = blockIdx.y * 128, n_blk = blockIdx.x * 128;
    const int w_m = (wave >> 1) * 64, w_n = (wave & 1) * 64;

    v4f acc[4][4] = {};

    const int slot0 = tid, slot1 = tid + 256;
    const int rowS0 = slot0 >> 2, chS0 = slot0 & 3;   // row 0..63, 16B chunk 0..3
    const int rowS1 = slot1 >> 2, chS1 = slot1 & 3;   // row 64..127

    const unsigned short* pa0 = A  + (size_t)(m_blk + rowS0) * K + chS0 * 8;
    const unsigned short* pa1 = A  + (size_t)(m_blk + rowS1) * K + chS1 * 8;
    const unsigned short* pb0 = Bt + (size_t)(n_blk + rowS0) * K + chS0 * 8;
    const unsigned short* pb1 = Bt + (size_t)(n_blk + rowS1) * K + chS1 * 8;

    unsigned short* lA0 = As + slot0 * 8;   // = As + tid*16B  (linear in lane)
    unsigned short* lA1 = As + slot1 * 8;
    unsigned short* lB0 = Bs + slot0 * 8;
    unsigned short* lB1 = Bs + slot1 * 8;

    for (int k0 = 0; k0 < K; k0 += 32) {
        gload16(pa0 + k0, lA0);
        gload16(pa1 + k0, lA1);
        gload16(pb0 + k0, lB0);
        gload16(pb1 + k0, lB1);
        __syncthreads();                     // drains vmcnt -> LDS tile complete
        bf16x8 af[4], bf[4];
#pragma unroll
        for (int i = 0; i < 4; i++)
            af[i] = *(const bf16x8*)(As + (w_m + i * 16 + r16) * 32 + quad * 8);
#pragma unroll
        for (int j = 0; j < 4; j++)
            bf[j] = *(const bf16x8*)(Bs + (w_n + j * 16 + r16) * 32 + quad * 8);
#pragma unroll
        for (int i = 0; i < 4; i++)
#pragma unroll
            for (int j = 0; j < 4; j++)
                acc[i][j] = __builtin_amdgcn_mfma_f32_16x16x32_bf16(af[i], bf[j], acc[i][j], 0, 0, 0);
        __syncthreads();
    }

#pragma unroll
    for (int j = 0; j < 4; j++) {
        int gcol = n_blk + w_n + j * 16 + r16;
        float bv = bias[gcol];
#pragma unroll
        for (int i = 0; i < 4; i++) {
            int grow = m_blk + w_m + i * 16 + quad * 4;
#pragma unroll
            for (int r = 0; r < 4; r++) {
                float v = acc[i][j][r] + bv;
                if (relu) v = fmaxf(v, 0.f);
                C[(size_t)(grow + r) * N + gcol] = f2bf(v);
            }
        }
    }
}

// ---------------- fused gather + dot-interaction + top-input build ----------------
// one wave per sample; feat rows: 0 = bot_out, 1..26 = emb rows. Gram via MFMA (a==b frags).
#define FS 136   // feat row stride in shorts (16B-aligned, breaks worst bank conflicts)
__global__ __launch_bounds__(256) void interact(const float* __restrict__ x,
                                                const float* __restrict__ emb,
                                                const unsigned short* __restrict__ h2,
                                                unsigned short* __restrict__ top_in) {
    __shared__ __align__(16) unsigned short feat[4][32 * FS];
    __shared__ __align__(16) unsigned short rowb[4][512];
    const int wave = threadIdx.x >> 6, lane = threadIdx.x & 63;
    const int s = blockIdx.x * 4 + wave;
    unsigned short* fw = feat[wave];
    unsigned short* rb = rowb[wave];
    const int quad = lane >> 4, r16 = lane & 15;

    int cat = 0;
    if (lane < 26) cat = (int)x[(size_t)s * 39 + 13 + lane];   // exact: ids < 2^24
    if (lane < 16)                                              // bot_out -> feat row 0
        *(uint4*)(fw + lane * 8) = *(const uint4*)(h2 + (size_t)s * 128 + lane * 8);
#pragma unroll
    for (int i = 0; i < 13; i++) {                              // 26 rows x 32 float4
        int t = i * 64 + lane;
        int row = t >> 5, c4 = t & 31;
        int id = __shfl(cat, row);
        float4 v = *(const float4*)(emb + (size_t)id * 128 + c4 * 4);
        ushort4 o;
        o.x = f2bf(v.x); o.y = f2bf(v.y); o.z = f2bf(v.z); o.w = f2bf(v.w);
        *(ushort4*)(fw + (size_t)(row + 1) * FS + c4 * 4) = o;
    }
    // Gram: tiles (0,0),(0,1),(1,1) of 16x16; rows>=27 feed only discarded entries.
    v4f c00 = {0,0,0,0}, c01 = {0,0,0,0}, c11 = {0,0,0,0};
#pragma unroll
    for (int kc = 0; kc < 4; kc++) {
        bf16x8 a0 = *(const bf16x8*)(fw + r16 * FS + kc * 32 + quad * 8);
        bf16x8 a1 = *(const bf16x8*)(fw + (16 + r16) * FS + kc * 32 + quad * 8);
        c00 = __builtin_amdgcn_mfma_f32_16x16x32_bf16(a0, a0, c00, 0, 0, 0);
        c01 = __builtin_amdgcn_mfma_f32_16x16x32_bf16(a0, a1, c01, 0, 0, 0);
        c11 = __builtin_amdgcn_mfma_f32_16x16x32_bf16(a1, a1, c11, 0, 0, 0);
    }
    // build 512-wide top_in row in LDS: [0..127]=bot_out, [128..505]=triu, [506..511]=0
    if (lane < 16) *(uint4*)(rb + lane * 8) = *(const uint4*)(fw + lane * 8);
    if (lane < 6) rb[506 + lane] = 0;
#pragma unroll
    for (int r = 0; r < 4; r++) {
        int i = quad * 4 + r;
        int j = r16;
        if (i <= j)
            rb[128 + i * 27 - (i * (i - 1)) / 2 + (j - i)] = f2bf(c00[r]);
        int j2 = 16 + r16;
        if (j2 < 27) {
            rb[128 + i * 27 - (i * (i - 1)) / 2 + (j2 - i)] = f2bf(c01[r]);
            int ii = 16 + quad * 4 + r;
            if (ii <= j2)
                rb[128 + ii * 27 - (ii * (ii - 1)) / 2 + (j2 - ii)] = f2bf(c11[r]);
        }
    }
    *(uint4*)(top_in + (size_t)s * 512 + lane * 8) = *(const uint4*)(rb + lane * 8);
}

// ---------------- final layer: [B,256] @ [256,1] + b -> fp32 ----------------
__global__ __launch_bounds__(256) void top_final(const unsigned short* __restrict__ ht3,
                                                 const float* __restrict__ w,
                                                 const float* __restrict__ b,
                                                 float* __restrict__ out) {
    int wave = threadIdx.x >> 6, lane = threadIdx.x & 63;
    int row = blockIdx.x * 4 + wave;
    ushort4 av = *(const ushort4*)(ht3 + (size_t)row * 256 + lane * 4);
    float4 wv = *(const float4*)(w + lane * 4);
    float s = bf2f(av.x) * wv.x + bf2f(av.y) * wv.y + bf2f(av.z) * wv.z + bf2f(av.w) * wv.w;
#pragma unroll
    for (int off = 32; off; off >>= 1) s += __shfl_down(s, off);
    if (lane == 0) out[row] = s + b[0];
}

// ---------------- launch ----------------
extern "C" void kernel_launch(void* const* d_in, const int* in_sizes, int n_in,
                              void* d_out, int out_size, void* d_ws, size_t ws_size,
                              hipStream_t stream) {
    (void)in_sizes; (void)n_in; (void)out_size; (void)ws_size;
    const float* x   = (const float*)d_in[0];
    const float* bw0 = (const float*)d_in[2];
    const float* bb0 = (const float*)d_in[3];
    const float* bw1 = (const float*)d_in[4];
    const float* bb1 = (const float*)d_in[5];
    const float* bw2 = (const float*)d_in[6];
    const float* bb2 = (const float*)d_in[7];
    const float* emb = (const float*)d_in[8];
    const float* tw0 = (const float*)d_in[9];
    const float* tb0 = (const float*)d_in[10];
    const float* tw1 = (const float*)d_in[11];
    const float* tb1 = (const float*)d_in[12];
    const float* tw2 = (const float*)d_in[13];
    const float* tb2 = (const float*)d_in[14];
    const float* tw3 = (const float*)d_in[15];
    const float* tb3 = (const float*)d_in[16];
    const float* tw4 = (const float*)d_in[17];
    const float* tb4 = (const float*)d_in[18];
    float* out = (float*)d_out;

    char* ws = (char*)d_ws;
    size_t off = 0;
    auto alloc = [&](size_t bytes) {
        void* p = ws + off;
        off += (bytes + 255) & ~(size_t)255;
        return p;
    };
    unsigned short* bw1t = (unsigned short*)alloc((size_t)256 * 512 * 2);
    unsigned short* bw2t = (unsigned short*)alloc((size_t)128 * 256 * 2);
    unsigned short* tw0t = (unsigned short*)alloc((size_t)1024 * 512 * 2);
    unsigned short* tw1t = (unsigned short*)alloc((size_t)1024 * 1024 * 2);
    unsigned short* tw2t = (unsigned short*)alloc((size_t)512 * 1024 * 2);
    unsigned short* tw3t = (unsigned short*)alloc((size_t)256 * 512 * 2);
    unsigned short* h2   = (unsigned short*)alloc((size_t)M_BATCH * 128 * 2);
    unsigned short* bufA = (unsigned short*)alloc((size_t)M_BATCH * 1024 * 2);
    unsigned short* bufB = (unsigned short*)alloc((size_t)M_BATCH * 1024 * 2);

    unsigned short* h0     = bufA;   // dead after b1
    unsigned short* h1     = bufB;   // dead after b2
    unsigned short* top_in = bufA;   // dead after t0
    unsigned short* ht0    = bufB;   // dead after t1
    unsigned short* ht1    = bufA;   // dead after t2
    unsigned short* ht2    = bufB;   // dead after t3
    unsigned short* ht3    = bufA;

    dim3 blk(256);
    // weight prep (fp32 [K,N] -> bf16 [N,Kpad])
    wprep<<<dim3(256 / 32,  512 / 32),  blk, 0, stream>>>(bw1,  bw1t, 512,  256,  512);
    wprep<<<dim3(128 / 32,  256 / 32),  blk, 0, stream>>>(bw2,  bw2t, 256,  128,  256);
    wprep<<<dim3(1024 / 32, 512 / 32),  blk, 0, stream>>>(tw0,  tw0t, 506,  1024, 512);
    wprep<<<dim3(1024 / 32, 1024 / 32), blk, 0, stream>>>(tw1,  tw1t, 1024, 1024, 1024);
    wprep<<<dim3(512 / 32,  1024 / 32), blk, 0, stream>>>(tw2,  tw2t, 1024, 512,  1024);
    wprep<<<dim3(256 / 32,  512 / 32),  blk, 0, stream>>>(tw3,  tw3t, 512,  256,  512);

    // bottom MLP
    bot0<<<dim3(M_BATCH * 512 / 256), blk, 0, stream>>>(x, bw0, bb0, h0);
    gemm_bt<<<dim3(256 / 128, M_BATCH / 128), blk, 0, stream>>>(h0, bw1t, bb1, h1, 256, 512, 1);
    gemm_bt<<<dim3(128 / 128, M_BATCH / 128), blk, 0, stream>>>(h1, bw2t, bb2, h2, 128, 256, 1);

    // gather + interaction + top-input build
    interact<<<dim3(M_BATCH / 4), blk, 0, stream>>>(x, emb, h2, top_in);

    // top MLP
    gemm_bt<<<dim3(1024 / 128, M_BATCH / 128), blk, 0, stream>>>(top_in, tw0t, tb0, ht0, 1024, 512, 1);
    gemm_bt<<<dim3(1024 / 128, M_BATCH / 128), blk, 0, stream>>>(ht0, tw1t, tb1, ht1, 1024, 1024, 1);
    gemm_bt<<<dim3(512 / 128,  M_BATCH / 128), blk, 0, stream>>>(ht1, tw2t, tb2, ht2, 512, 1024, 1);
    gemm_bt<<<dim3(256 / 128,  M_BATCH / 128), blk, 0, stream>>>(ht2, tw3t, tb3, ht3, 256, 512, 1);
    top_final<<<dim3(M_BATCH / 4), blk, 0, stream>>>(ht3, tw4, tb4, out);
}

// Round 3
// 847.340 us; speedup vs baseline: 1.0023x; 1.0023x over previous
//
#include <hip/hip_runtime.h>

// ---------------- common types / helpers ----------------
typedef float v4f  __attribute__((ext_vector_type(4)));
typedef __bf16 bf16x8 __attribute__((ext_vector_type(8)));

__device__ __forceinline__ unsigned short f2bf(float f) {
    unsigned u = __builtin_bit_cast(unsigned, f);
    u += 0x7FFFu + ((u >> 16) & 1u);          // RNE
    return (unsigned short)(u >> 16);
}
__device__ __forceinline__ float bf2f(unsigned short h) {
    return __builtin_bit_cast(float, (unsigned)h << 16);
}

// async global->LDS DMA, 16B per lane. LDS dest must be wave-uniform base + lane*16.
__device__ __forceinline__ void gload16(const unsigned short* g, unsigned short* l) {
    __builtin_amdgcn_global_load_lds(
        (const __attribute__((address_space(1))) unsigned int*)g,
        (__attribute__((address_space(3))) unsigned int*)l, 16, 0, 0);
}

#define M_BATCH 16384

// ---------------- weight prep: fp32 [K,N] -> bf16 [N,Kpad] (transposed) ----------------
__global__ __launch_bounds__(256) void wprep(const float* __restrict__ in,
                                             unsigned short* __restrict__ out,
                                             int K, int N, int Kpad) {
    __shared__ float tile[32][33];
    int tx = threadIdx.x & 31;
    int ty = threadIdx.x >> 5;               // 0..7
    int n0 = blockIdx.x * 32, k0 = blockIdx.y * 32;
#pragma unroll
    for (int i = 0; i < 32; i += 8) {
        int k = k0 + ty + i, n = n0 + tx;
        tile[ty + i][tx] = (k < K && n < N) ? in[(size_t)k * N + n] : 0.f;
    }
    __syncthreads();
#pragma unroll
    for (int i = 0; i < 32; i += 8) {
        int n = n0 + ty + i, k = k0 + tx;
        if (n < N && k < Kpad) out[(size_t)n * Kpad + k] = f2bf(tile[tx][ty + i]);
    }
}

// ---------------- bottom layer 0: [B,13] @ [13,512] + b, relu -> bf16 ----------------
__global__ __launch_bounds__(256) void bot0(const float* __restrict__ x,
                                            const float* __restrict__ w,
                                            const float* __restrict__ b,
                                            unsigned short* __restrict__ h0) {
    int gid = blockIdx.x * 256 + threadIdx.x;          // M*512 threads
    int row = gid >> 9, col = gid & 511;
    const float* xr = x + (size_t)row * 39;
    float acc = b[col];
#pragma unroll
    for (int k = 0; k < 13; k++) acc += xr[k] * w[k * 512 + col];
    h0[gid] = f2bf(fmaxf(acc, 0.f));
}

// ---------------- generic bf16 MFMA GEMM: C = act(A[M,K] @ Bt[N,K]^T + bias) ----------------
// 128x128 tile, 4 waves, 4x4 16x16x32 acc per wave, BK=32.
// Double-buffered LDS + global_load_lds: stage tile t+1 BEFORE computing tile t,
// drain with vmcnt(0)+s_barrier AFTER compute ("minimum 2-phase", one barrier/K-step).
// All K are multiples of 64 -> unroll x2 with named buffers (no runtime-indexed ptrs).
__global__ __launch_bounds__(256) void gemm_bt(const unsigned short* __restrict__ A,
                                               const unsigned short* __restrict__ Bt,
                                               const float* __restrict__ bias,
                                               unsigned short* __restrict__ C,
                                               int N, int K, int relu) {
    __shared__ __align__(16) unsigned short As0[128 * 32];
    __shared__ __align__(16) unsigned short Bs0[128 * 32];
    __shared__ __align__(16) unsigned short As1[128 * 32];
    __shared__ __align__(16) unsigned short Bs1[128 * 32];
    const int tid  = threadIdx.x;
    const int wave = tid >> 6, lane = tid & 63;
    const int quad = lane >> 4, r16 = lane & 15;
    const int m_blk = blockIdx.y * 128, n_blk = blockIdx.x * 128;
    const int w_m = (wave >> 1) * 64, w_n = (wave & 1) * 64;

    v4f acc[4][4] = {};

    const int slot0 = tid, slot1 = tid + 256;
    const int rowS0 = slot0 >> 2, chS0 = slot0 & 3;   // row 0..63, 16B chunk 0..3
    const int rowS1 = slot1 >> 2, chS1 = slot1 & 3;   // row 64..127

    const unsigned short* pa0 = A  + (size_t)(m_blk + rowS0) * K + chS0 * 8;
    const unsigned short* pa1 = A  + (size_t)(m_blk + rowS1) * K + chS1 * 8;
    const unsigned short* pb0 = Bt + (size_t)(n_blk + rowS0) * K + chS0 * 8;
    const unsigned short* pb1 = Bt + (size_t)(n_blk + rowS1) * K + chS1 * 8;

#define STAGE(AsX, BsX, kk)                                   \
    do {                                                      \
        gload16(pa0 + (kk), AsX + slot0 * 8);                 \
        gload16(pa1 + (kk), AsX + slot1 * 8);                 \
        gload16(pb0 + (kk), BsX + slot0 * 8);                 \
        gload16(pb1 + (kk), BsX + slot1 * 8);                 \
    } while (0)

#define DRAIN_BAR()                                           \
    do {                                                      \
        asm volatile("s_waitcnt vmcnt(0)" ::: "memory");      \
        __builtin_amdgcn_s_barrier();                         \
        __builtin_amdgcn_sched_barrier(0);                    \
    } while (0)

#define COMPUTE(AsX, BsX)                                                         \
    do {                                                                          \
        bf16x8 af[4], bf[4];                                                      \
        _Pragma("unroll")                                                         \
        for (int i = 0; i < 4; i++)                                               \
            af[i] = *(const bf16x8*)(AsX + (w_m + i * 16 + r16) * 32 + quad * 8); \
        _Pragma("unroll")                                                         \
        for (int j = 0; j < 4; j++)                                               \
            bf[j] = *(const bf16x8*)(BsX + (w_n + j * 16 + r16) * 32 + quad * 8); \
        _Pragma("unroll")                                                         \
        for (int i = 0; i < 4; i++)                                               \
            _Pragma("unroll")                                                     \
            for (int j = 0; j < 4; j++)                                           \
                acc[i][j] = __builtin_amdgcn_mfma_f32_16x16x32_bf16(              \
                    af[i], bf[j], acc[i][j], 0, 0, 0);                            \
    } while (0)

    // prologue: tile 0 -> buf0
    STAGE(As0, Bs0, 0);
    DRAIN_BAR();

    for (int k0 = 0; k0 < K; k0 += 64) {
        // phase 0: stage k0+32 -> buf1 (always valid: k0+32 < K), compute buf0
        STAGE(As1, Bs1, k0 + 32);
        COMPUTE(As0, Bs0);
        DRAIN_BAR();
        // phase 1: stage k0+64 -> buf0 (if any), compute buf1
        if (k0 + 64 < K) STAGE(As0, Bs0, k0 + 64);
        COMPUTE(As1, Bs1);
        DRAIN_BAR();
    }
#undef STAGE
#undef DRAIN_BAR
#undef COMPUTE

#pragma unroll
    for (int j = 0; j < 4; j++) {
        int gcol = n_blk + w_n + j * 16 + r16;
        float bv = bias[gcol];
#pragma unroll
        for (int i = 0; i < 4; i++) {
            int grow = m_blk + w_m + i * 16 + quad * 4;
#pragma unroll
            for (int r = 0; r < 4; r++) {
                float v = acc[i][j][r] + bv;
                if (relu) v = fmaxf(v, 0.f);
                C[(size_t)(grow + r) * N + gcol] = f2bf(v);
            }
        }
    }
}

// ---------------- fused gather + dot-interaction + top-input build ----------------
// one wave per sample; feat rows: 0 = bot_out, 1..26 = emb rows. Gram via MFMA (a==b frags).
#define FS 136   // feat row stride in shorts (16B-aligned, breaks worst bank conflicts)
__global__ __launch_bounds__(256) void interact(const float* __restrict__ x,
                                                const float* __restrict__ emb,
                                                const unsigned short* __restrict__ h2,
                                                unsigned short* __restrict__ top_in) {
    __shared__ __align__(16) unsigned short feat[4][32 * FS];
    __shared__ __align__(16) unsigned short rowb[4][512];
    const int wave = threadIdx.x >> 6, lane = threadIdx.x & 63;
    const int s = blockIdx.x * 4 + wave;
    unsigned short* fw = feat[wave];
    unsigned short* rb = rowb[wave];
    const int quad = lane >> 4, r16 = lane & 15;

    int cat = 0;
    if (lane < 26) cat = (int)x[(size_t)s * 39 + 13 + lane];   // exact: ids < 2^24
    if (lane < 16)                                              // bot_out -> feat row 0
        *(uint4*)(fw + lane * 8) = *(const uint4*)(h2 + (size_t)s * 128 + lane * 8);
#pragma unroll
    for (int i = 0; i < 13; i++) {                              // 26 rows x 32 float4
        int t = i * 64 + lane;
        int row = t >> 5, c4 = t & 31;
        int id = __shfl(cat, row);
        float4 v = *(const float4*)(emb + (size_t)id * 128 + c4 * 4);
        ushort4 o;
        o.x = f2bf(v.x); o.y = f2bf(v.y); o.z = f2bf(v.z); o.w = f2bf(v.w);
        *(ushort4*)(fw + (size_t)(row + 1) * FS + c4 * 4) = o;
    }
    // Gram: tiles (0,0),(0,1),(1,1) of 16x16; rows>=27 feed only discarded entries.
    v4f c00 = {0,0,0,0}, c01 = {0,0,0,0}, c11 = {0,0,0,0};
#pragma unroll
    for (int kc = 0; kc < 4; kc++) {
        bf16x8 a0 = *(const bf16x8*)(fw + r16 * FS + kc * 32 + quad * 8);
        bf16x8 a1 = *(const bf16x8*)(fw + (16 + r16) * FS + kc * 32 + quad * 8);
        c00 = __builtin_amdgcn_mfma_f32_16x16x32_bf16(a0, a0, c00, 0, 0, 0);
        c01 = __builtin_amdgcn_mfma_f32_16x16x32_bf16(a0, a1, c01, 0, 0, 0);
        c11 = __builtin_amdgcn_mfma_f32_16x16x32_bf16(a1, a1, c11, 0, 0, 0);
    }
    // build 512-wide top_in row in LDS: [0..127]=bot_out, [128..505]=triu, [506..511]=0
    if (lane < 16) *(uint4*)(rb + lane * 8) = *(const uint4*)(fw + lane * 8);
    if (lane < 6) rb[506 + lane] = 0;
#pragma unroll
    for (int r = 0; r < 4; r++) {
        int i = quad * 4 + r;
        int j = r16;
        if (i <= j)
            rb[128 + i * 27 - (i * (i - 1)) / 2 + (j - i)] = f2bf(c00[r]);
        int j2 = 16 + r16;
        if (j2 < 27) {
            rb[128 + i * 27 - (i * (i - 1)) / 2 + (j2 - i)] = f2bf(c01[r]);
            int ii = 16 + quad * 4 + r;
            if (ii <= j2)
                rb[128 + ii * 27 - (ii * (ii - 1)) / 2 + (j2 - ii)] = f2bf(c11[r]);
        }
    }
    *(uint4*)(top_in + (size_t)s * 512 + lane * 8) = *(const uint4*)(rb + lane * 8);
}

// ---------------- final layer: [B,256] @ [256,1] + b -> fp32 ----------------
__global__ __launch_bounds__(256) void top_final(const unsigned short* __restrict__ ht3,
                                                 const float* __restrict__ w,
                                                 const float* __restrict__ b,
                                                 float* __restrict__ out) {
    int wave = threadIdx.x >> 6, lane = threadIdx.x & 63;
    int row = blockIdx.x * 4 + wave;
    ushort4 av = *(const ushort4*)(ht3 + (size_t)row * 256 + lane * 4);
    float4 wv = *(const float4*)(w + lane * 4);
    float s = bf2f(av.x) * wv.x + bf2f(av.y) * wv.y + bf2f(av.z) * wv.z + bf2f(av.w) * wv.w;
#pragma unroll
    for (int off = 32; off; off >>= 1) s += __shfl_down(s, off);
    if (lane == 0) out[row] = s + b[0];
}

// ---------------- launch ----------------
extern "C" void kernel_launch(void* const* d_in, const int* in_sizes, int n_in,
                              void* d_out, int out_size, void* d_ws, size_t ws_size,
                              hipStream_t stream) {
    (void)in_sizes; (void)n_in; (void)out_size; (void)ws_size;
    const float* x   = (const float*)d_in[0];
    const float* bw0 = (const float*)d_in[2];
    const float* bb0 = (const float*)d_in[3];
    const float* bw1 = (const float*)d_in[4];
    const float* bb1 = (const float*)d_in[5];
    const float* bw2 = (const float*)d_in[6];
    const float* bb2 = (const float*)d_in[7];
    const float* emb = (const float*)d_in[8];
    const float* tw0 = (const float*)d_in[9];
    const float* tb0 = (const float*)d_in[10];
    const float* tw1 = (const float*)d_in[11];
    const float* tb1 = (const float*)d_in[12];
    const float* tw2 = (const float*)d_in[13];
    const float* tb2 = (const float*)d_in[14];
    const float* tw3 = (const float*)d_in[15];
    const float* tb3 = (const float*)d_in[16];
    const float* tw4 = (const float*)d_in[17];
    const float* tb4 = (const float*)d_in[18];
    float* out = (float*)d_out;

    char* ws = (char*)d_ws;
    size_t off = 0;
    auto alloc = [&](size_t bytes) {
        void* p = ws + off;
        off += (bytes + 255) & ~(size_t)255;
        return p;
    };
    unsigned short* bw1t = (unsigned short*)alloc((size_t)256 * 512 * 2);
    unsigned short* bw2t = (unsigned short*)alloc((size_t)128 * 256 * 2);
    unsigned short* tw0t = (unsigned short*)alloc((size_t)1024 * 512 * 2);
    unsigned short* tw1t = (unsigned short*)alloc((size_t)1024 * 1024 * 2);
    unsigned short* tw2t = (unsigned short*)alloc((size_t)512 * 1024 * 2);
    unsigned short* tw3t = (unsigned short*)alloc((size_t)256 * 512 * 2);
    unsigned short* h2   = (unsigned short*)alloc((size_t)M_BATCH * 128 * 2);
    unsigned short* bufA = (unsigned short*)alloc((size_t)M_BATCH * 1024 * 2);
    unsigned short* bufB = (unsigned short*)alloc((size_t)M_BATCH * 1024 * 2);

    unsigned short* h0     = bufA;   // dead after b1
    unsigned short* h1     = bufB;   // dead after b2
    unsigned short* top_in = bufA;   // dead after t0
    unsigned short* ht0    = bufB;   // dead after t1
    unsigned short* ht1    = bufA;   // dead after t2
    unsigned short* ht2    = bufB;   // dead after t3
    unsigned short* ht3    = bufA;

    dim3 blk(256);
    // weight prep (fp32 [K,N] -> bf16 [N,Kpad])
    wprep<<<dim3(256 / 32,  512 / 32),  blk, 0, stream>>>(bw1,  bw1t, 512,  256,  512);
    wprep<<<dim3(128 / 32,  256 / 32),  blk, 0, stream>>>(bw2,  bw2t, 256,  128,  256);
    wprep<<<dim3(1024 / 32, 512 / 32),  blk, 0, stream>>>(tw0,  tw0t, 506,  1024, 512);
    wprep<<<dim3(1024 / 32, 1024 / 32), blk, 0, stream>>>(tw1,  tw1t, 1024, 1024, 1024);
    wprep<<<dim3(512 / 32,  1024 / 32), blk, 0, stream>>>(tw2,  tw2t, 1024, 512,  1024);
    wprep<<<dim3(256 / 32,  512 / 32),  blk, 0, stream>>>(tw3,  tw3t, 512,  256,  512);

    // bottom MLP
    bot0<<<dim3(M_BATCH * 512 / 256), blk, 0, stream>>>(x, bw0, bb0, h0);
    gemm_bt<<<dim3(256 / 128, M_BATCH / 128), blk, 0, stream>>>(h0, bw1t, bb1, h1, 256, 512, 1);
    gemm_bt<<<dim3(128 / 128, M_BATCH / 128), blk, 0, stream>>>(h1, bw2t, bb2, h2, 128, 256, 1);

    // gather + interaction + top-input build
    interact<<<dim3(M_BATCH / 4), blk, 0, stream>>>(x, emb, h2, top_in);

    // top MLP
    gemm_bt<<<dim3(1024 / 128, M_BATCH / 128), blk, 0, stream>>>(top_in, tw0t, tb0, ht0, 1024, 512, 1);
    gemm_bt<<<dim3(1024 / 128, M_BATCH / 128), blk, 0, stream>>>(ht0, tw1t, tb1, ht1, 1024, 1024, 1);
    gemm_bt<<<dim3(512 / 128,  M_BATCH / 128), blk, 0, stream>>>(ht1, tw2t, tb2, ht2, 512, 1024, 1);
    gemm_bt<<<dim3(256 / 128,  M_BATCH / 128), blk, 0, stream>>>(ht2, tw3t, tb3, ht3, 256, 512, 1);
    top_final<<<dim3(M_BATCH / 4), blk, 0, stream>>>(ht3, tw4, tb4, out);
}

// Round 4
// 811.165 us; speedup vs baseline: 1.0470x; 1.0446x over previous
//
#include <hip/hip_runtime.h>

// ---------------- common types / helpers ----------------
typedef float v4f  __attribute__((ext_vector_type(4)));
typedef __bf16 bf16x8 __attribute__((ext_vector_type(8)));

__device__ __forceinline__ unsigned short f2bf(float f) {
    unsigned u = __builtin_bit_cast(unsigned, f);
    u += 0x7FFFu + ((u >> 16) & 1u);          // RNE
    return (unsigned short)(u >> 16);
}
__device__ __forceinline__ float bf2f(unsigned short h) {
    return __builtin_bit_cast(float, (unsigned)h << 16);
}

#define M_BATCH 16384

// ---------------- weight prep: fp32 [K,N] -> bf16 [N,Kpad] (transposed) ----------------
__global__ __launch_bounds__(256) void wprep(const float* __restrict__ in,
                                             unsigned short* __restrict__ out,
                                             int K, int N, int Kpad) {
    __shared__ float tile[32][33];
    int tx = threadIdx.x & 31;
    int ty = threadIdx.x >> 5;               // 0..7
    int n0 = blockIdx.x * 32, k0 = blockIdx.y * 32;
#pragma unroll
    for (int i = 0; i < 32; i += 8) {
        int k = k0 + ty + i, n = n0 + tx;
        tile[ty + i][tx] = (k < K && n < N) ? in[(size_t)k * N + n] : 0.f;
    }
    __syncthreads();
#pragma unroll
    for (int i = 0; i < 32; i += 8) {
        int n = n0 + ty + i, k = k0 + tx;
        if (n < N && k < Kpad) out[(size_t)n * Kpad + k] = f2bf(tile[tx][ty + i]);
    }
}

// ---------------- bottom layer 0: [B,13] @ [13,512] + b, relu -> bf16 ----------------
__global__ __launch_bounds__(256) void bot0(const float* __restrict__ x,
                                            const float* __restrict__ w,
                                            const float* __restrict__ b,
                                            unsigned short* __restrict__ h0) {
    int gid = blockIdx.x * 256 + threadIdx.x;          // M*512 threads
    int row = gid >> 9, col = gid & 511;
    const float* xr = x + (size_t)row * 39;
    float acc = b[col];
#pragma unroll
    for (int k = 0; k < 13; k++) acc += xr[k] * w[k * 512 + col];
    h0[gid] = f2bf(fmaxf(acc, 0.f));
}

// ---------------- generic bf16 MFMA GEMM: C = act(A[M,K] @ Bt[N,K]^T + bias) ----------------
// 128x128 tile, 4 waves, 4x4 16x16x32 acc/wave, BK=32.
// Reg-prefetch staging (proven best) + LDS double-buffer + ONE raw s_barrier per K-step
// with counted s_waitcnt vmcnt(4) (never drain to 0 in the loop). Two named reg sets,
// dummy tail loads keep the in-flight count uniform (vmcnt arithmetic stays valid).
// XCD-chunked block swizzle: consecutive dispatch ids share an A-panel; remap so
// panel-sharers land on the same XCD's L2 (all grids are %8 == 0).
__global__ __launch_bounds__(256) void gemm_bt(const unsigned short* __restrict__ A,
                                               const unsigned short* __restrict__ Bt,
                                               const float* __restrict__ bias,
                                               unsigned short* __restrict__ C,
                                               int N, int K, int relu) {
    __shared__ __align__(16) unsigned short As0[128 * 32];
    __shared__ __align__(16) unsigned short Bs0[128 * 32];
    __shared__ __align__(16) unsigned short As1[128 * 32];
    __shared__ __align__(16) unsigned short Bs1[128 * 32];
    const int tid  = threadIdx.x;
    const int wave = tid >> 6, lane = tid & 63;
    const int quad = lane >> 4, r16 = lane & 15;

    // XCD-aware bijective swizzle of the flattened block id (dispatch order is x-fastest)
    const int gx = gridDim.x;
    const int nwg = gx * gridDim.y;
    int d = blockIdx.y * gx + blockIdx.x;
    int logical = d;
    if ((nwg & 7) == 0) logical = (d & 7) * (nwg >> 3) + (d >> 3);
    const int bx = logical % gx, by = logical / gx;

    const int m_blk = by * 128, n_blk = bx * 128;
    const int w_m = (wave >> 1) * 64, w_n = (wave & 1) * 64;

    v4f acc[4][4] = {};

    const int slot0 = tid, slot1 = tid + 256;
    const int rowS0 = slot0 >> 2, chS0 = slot0 & 3;   // row 0..63, 16B chunk 0..3
    const int rowS1 = slot1 >> 2, chS1 = slot1 & 3;   // row 64..127

    const unsigned short* pa0 = A  + (size_t)(m_blk + rowS0) * K + chS0 * 8;
    const unsigned short* pa1 = A  + (size_t)(m_blk + rowS1) * K + chS1 * 8;
    const unsigned short* pb0 = Bt + (size_t)(n_blk + rowS0) * K + chS0 * 8;
    const unsigned short* pb1 = Bt + (size_t)(n_blk + rowS1) * K + chS1 * 8;

    const int T = K >> 5;                    // K-steps; even for all layers (K%64==0)

#define LOADSET(sA0, sA1, sB0, sB1, kk)                       \
    do {                                                      \
        sA0 = *(const uint4*)(pa0 + (kk));                    \
        sA1 = *(const uint4*)(pa1 + (kk));                    \
        sB0 = *(const uint4*)(pb0 + (kk));                    \
        sB1 = *(const uint4*)(pb1 + (kk));                    \
    } while (0)

#define WRITESET(AsX, BsX, sA0, sA1, sB0, sB1)                \
    do {                                                      \
        ((uint4*)AsX)[slot0] = sA0;                           \
        ((uint4*)AsX)[slot1] = sA1;                           \
        ((uint4*)BsX)[slot0] = sB0;                           \
        ((uint4*)BsX)[slot1] = sB1;                           \
    } while (0)

#define COMPUTE(AsX, BsX)                                                         \
    do {                                                                          \
        bf16x8 af[4], bf[4];                                                      \
        _Pragma("unroll")                                                         \
        for (int i = 0; i < 4; i++)                                               \
            af[i] = *(const bf16x8*)(AsX + (w_m + i * 16 + r16) * 32 + quad * 8); \
        _Pragma("unroll")                                                         \
        for (int j = 0; j < 4; j++)                                               \
            bf[j] = *(const bf16x8*)(BsX + (w_n + j * 16 + r16) * 32 + quad * 8); \
        _Pragma("unroll")                                                         \
        for (int i = 0; i < 4; i++)                                               \
            _Pragma("unroll")                                                     \
            for (int j = 0; j < 4; j++)                                           \
                acc[i][j] = __builtin_amdgcn_mfma_f32_16x16x32_bf16(              \
                    af[i], bf[j], acc[i][j], 0, 0, 0);                            \
    } while (0)

#define WAIT_VM4()                                            \
    do {                                                      \
        asm volatile("s_waitcnt vmcnt(4)" ::: "memory");      \
        __builtin_amdgcn_sched_barrier(0);                    \
    } while (0)

#define LGKM0_BAR()                                           \
    do {                                                      \
        asm volatile("s_waitcnt lgkmcnt(0)" ::: "memory");    \
        __builtin_amdgcn_sched_barrier(0);                    \
        __builtin_amdgcn_s_barrier();                         \
    } while (0)

    uint4 aA0, aA1, aB0, aB1;                // set0
    uint4 bA0, bA1, bB0, bB1;                // set1

    // prologue: issue tiles 0 and 1 (8 loads in flight), stage tile 0 -> buf0
    LOADSET(aA0, aA1, aB0, aB1, 0);
    LOADSET(bA0, bA1, bB0, bB1, 32);
    WAIT_VM4();                              // set0 complete, set1 still in flight
    WRITESET(As0, Bs0, aA0, aA1, aB0, aB1);
    LGKM0_BAR();                             // buf0 visible to all waves

    for (int t = 0; t < T; t += 2) {
        // phase A: compute tile t (buf0); set1 = tile t+1 in flight
        {
            int kk = (t + 2 < T) ? (t + 2) * 32 : 0;      // dummy tail load keeps count
            LOADSET(aA0, aA1, aB0, aB1, kk);              // issue tile t+2 (8 in flight)
            COMPUTE(As0, Bs0);
            WAIT_VM4();                                   // set1 (older 4) complete
            WRITESET(As1, Bs1, bA0, bA1, bB0, bB1);       // stage tile t+1 -> buf1
            LGKM0_BAR();
        }
        // phase B: compute tile t+1 (buf1); set0 = tile t+2 in flight
        {
            int kk = (t + 3 < T) ? (t + 3) * 32 : 0;
            LOADSET(bA0, bA1, bB0, bB1, kk);              // issue tile t+3
            COMPUTE(As1, Bs1);
            WAIT_VM4();                                   // set0 complete
            WRITESET(As0, Bs0, aA0, aA1, aB0, aB1);       // stage tile t+2 -> buf0
            LGKM0_BAR();
        }
    }
#undef LOADSET
#undef WRITESET
#undef COMPUTE
#undef WAIT_VM4
#undef LGKM0_BAR

#pragma unroll
    for (int j = 0; j < 4; j++) {
        int gcol = n_blk + w_n + j * 16 + r16;
        float bv = bias[gcol];
#pragma unroll
        for (int i = 0; i < 4; i++) {
            int grow = m_blk + w_m + i * 16 + quad * 4;
#pragma unroll
            for (int r = 0; r < 4; r++) {
                float v = acc[i][j][r] + bv;
                if (relu) v = fmaxf(v, 0.f);
                C[(size_t)(grow + r) * N + gcol] = f2bf(v);
            }
        }
    }
}

// ---------------- fused gather + dot-interaction + top-input build ----------------
// one wave per sample; feat rows: 0 = bot_out, 1..26 = emb rows. Gram via MFMA (a==b frags).
#define FS 136   // feat row stride in shorts (16B-aligned, breaks worst bank conflicts)
__global__ __launch_bounds__(256) void interact(const float* __restrict__ x,
                                                const float* __restrict__ emb,
                                                const unsigned short* __restrict__ h2,
                                                unsigned short* __restrict__ top_in) {
    __shared__ __align__(16) unsigned short feat[4][32 * FS];
    __shared__ __align__(16) unsigned short rowb[4][512];
    const int wave = threadIdx.x >> 6, lane = threadIdx.x & 63;
    const int s = blockIdx.x * 4 + wave;
    unsigned short* fw = feat[wave];
    unsigned short* rb = rowb[wave];
    const int quad = lane >> 4, r16 = lane & 15;

    int cat = 0;
    if (lane < 26) cat = (int)x[(size_t)s * 39 + 13 + lane];   // exact: ids < 2^24
    if (lane < 16)                                              // bot_out -> feat row 0
        *(uint4*)(fw + lane * 8) = *(const uint4*)(h2 + (size_t)s * 128 + lane * 8);
#pragma unroll
    for (int i = 0; i < 13; i++) {                              // 26 rows x 32 float4
        int t = i * 64 + lane;
        int row = t >> 5, c4 = t & 31;
        int id = __shfl(cat, row);
        float4 v = *(const float4*)(emb + (size_t)id * 128 + c4 * 4);
        ushort4 o;
        o.x = f2bf(v.x); o.y = f2bf(v.y); o.z = f2bf(v.z); o.w = f2bf(v.w);
        *(ushort4*)(fw + (size_t)(row + 1) * FS + c4 * 4) = o;
    }
    // Gram: tiles (0,0),(0,1),(1,1) of 16x16; rows>=27 feed only discarded entries.
    v4f c00 = {0,0,0,0}, c01 = {0,0,0,0}, c11 = {0,0,0,0};
#pragma unroll
    for (int kc = 0; kc < 4; kc++) {
        bf16x8 a0 = *(const bf16x8*)(fw + r16 * FS + kc * 32 + quad * 8);
        bf16x8 a1 = *(const bf16x8*)(fw + (16 + r16) * FS + kc * 32 + quad * 8);
        c00 = __builtin_amdgcn_mfma_f32_16x16x32_bf16(a0, a0, c00, 0, 0, 0);
        c01 = __builtin_amdgcn_mfma_f32_16x16x32_bf16(a0, a1, c01, 0, 0, 0);
        c11 = __builtin_amdgcn_mfma_f32_16x16x32_bf16(a1, a1, c11, 0, 0, 0);
    }
    // build 512-wide top_in row in LDS: [0..127]=bot_out, [128..505]=triu, [506..511]=0
    if (lane < 16) *(uint4*)(rb + lane * 8) = *(const uint4*)(fw + lane * 8);
    if (lane < 6) rb[506 + lane] = 0;
#pragma unroll
    for (int r = 0; r < 4; r++) {
        int i = quad * 4 + r;
        int j = r16;
        if (i <= j)
            rb[128 + i * 27 - (i * (i - 1)) / 2 + (j - i)] = f2bf(c00[r]);
        int j2 = 16 + r16;
        if (j2 < 27) {
            rb[128 + i * 27 - (i * (i - 1)) / 2 + (j2 - i)] = f2bf(c01[r]);
            int ii = 16 + quad * 4 + r;
            if (ii <= j2)
                rb[128 + ii * 27 - (ii * (ii - 1)) / 2 + (j2 - ii)] = f2bf(c11[r]);
        }
    }
    *(uint4*)(top_in + (size_t)s * 512 + lane * 8) = *(const uint4*)(rb + lane * 8);
}

// ---------------- final layer: [B,256] @ [256,1] + b -> fp32 ----------------
__global__ __launch_bounds__(256) void top_final(const unsigned short* __restrict__ ht3,
                                                 const float* __restrict__ w,
                                                 const float* __restrict__ b,
                                                 float* __restrict__ out) {
    int wave = threadIdx.x >> 6, lane = threadIdx.x & 63;
    int row = blockIdx.x * 4 + wave;
    ushort4 av = *(const ushort4*)(ht3 + (size_t)row * 256 + lane * 4);
    float4 wv = *(const float4*)(w + lane * 4);
    float s = bf2f(av.x) * wv.x + bf2f(av.y) * wv.y + bf2f(av.z) * wv.z + bf2f(av.w) * wv.w;
#pragma unroll
    for (int off = 32; off; off >>= 1) s += __shfl_down(s, off);
    if (lane == 0) out[row] = s + b[0];
}

// ---------------- launch ----------------
extern "C" void kernel_launch(void* const* d_in, const int* in_sizes, int n_in,
                              void* d_out, int out_size, void* d_ws, size_t ws_size,
                              hipStream_t stream) {
    (void)in_sizes; (void)n_in; (void)out_size; (void)ws_size;
    const float* x   = (const float*)d_in[0];
    const float* bw0 = (const float*)d_in[2];
    const float* bb0 = (const float*)d_in[3];
    const float* bw1 = (const float*)d_in[4];
    const float* bb1 = (const float*)d_in[5];
    const float* bw2 = (const float*)d_in[6];
    const float* bb2 = (const float*)d_in[7];
    const float* emb = (const float*)d_in[8];
    const float* tw0 = (const float*)d_in[9];
    const float* tb0 = (const float*)d_in[10];
    const float* tw1 = (const float*)d_in[11];
    const float* tb1 = (const float*)d_in[12];
    const float* tw2 = (const float*)d_in[13];
    const float* tb2 = (const float*)d_in[14];
    const float* tw3 = (const float*)d_in[15];
    const float* tb3 = (const float*)d_in[16];
    const float* tw4 = (const float*)d_in[17];
    const float* tb4 = (const float*)d_in[18];
    float* out = (float*)d_out;

    char* ws = (char*)d_ws;
    size_t off = 0;
    auto alloc = [&](size_t bytes) {
        void* p = ws + off;
        off += (bytes + 255) & ~(size_t)255;
        return p;
    };
    unsigned short* bw1t = (unsigned short*)alloc((size_t)256 * 512 * 2);
    unsigned short* bw2t = (unsigned short*)alloc((size_t)128 * 256 * 2);
    unsigned short* tw0t = (unsigned short*)alloc((size_t)1024 * 512 * 2);
    unsigned short* tw1t = (unsigned short*)alloc((size_t)1024 * 1024 * 2);
    unsigned short* tw2t = (unsigned short*)alloc((size_t)512 * 1024 * 2);
    unsigned short* tw3t = (unsigned short*)alloc((size_t)256 * 512 * 2);
    unsigned short* h2   = (unsigned short*)alloc((size_t)M_BATCH * 128 * 2);
    unsigned short* bufA = (unsigned short*)alloc((size_t)M_BATCH * 1024 * 2);
    unsigned short* bufB = (unsigned short*)alloc((size_t)M_BATCH * 1024 * 2);

    unsigned short* h0     = bufA;   // dead after b1
    unsigned short* h1     = bufB;   // dead after b2
    unsigned short* top_in = bufA;   // dead after t0
    unsigned short* ht0    = bufB;   // dead after t1
    unsigned short* ht1    = bufA;   // dead after t2
    unsigned short* ht2    = bufB;   // dead after t3
    unsigned short* ht3    = bufA;

    dim3 blk(256);
    // weight prep (fp32 [K,N] -> bf16 [N,Kpad])
    wprep<<<dim3(256 / 32,  512 / 32),  blk, 0, stream>>>(bw1,  bw1t, 512,  256,  512);
    wprep<<<dim3(128 / 32,  256 / 32),  blk, 0, stream>>>(bw2,  bw2t, 256,  128,  256);
    wprep<<<dim3(1024 / 32, 512 / 32),  blk, 0, stream>>>(tw0,  tw0t, 506,  1024, 512);
    wprep<<<dim3(1024 / 32, 1024 / 32), blk, 0, stream>>>(tw1,  tw1t, 1024, 1024, 1024);
    wprep<<<dim3(512 / 32,  1024 / 32), blk, 0, stream>>>(tw2,  tw2t, 1024, 512,  1024);
    wprep<<<dim3(256 / 32,  512 / 32),  blk, 0, stream>>>(tw3,  tw3t, 512,  256,  512);

    // bottom MLP
    bot0<<<dim3(M_BATCH * 512 / 256), blk, 0, stream>>>(x, bw0, bb0, h0);
    gemm_bt<<<dim3(256 / 128, M_BATCH / 128), blk, 0, stream>>>(h0, bw1t, bb1, h1, 256, 512, 1);
    gemm_bt<<<dim3(128 / 128, M_BATCH / 128), blk, 0, stream>>>(h1, bw2t, bb2, h2, 128, 256, 1);

    // gather + interaction + top-input build
    interact<<<dim3(M_BATCH / 4), blk, 0, stream>>>(x, emb, h2, top_in);

    // top MLP
    gemm_bt<<<dim3(1024 / 128, M_BATCH / 128), blk, 0, stream>>>(top_in, tw0t, tb0, ht0, 1024, 512, 1);
    gemm_bt<<<dim3(1024 / 128, M_BATCH / 128), blk, 0, stream>>>(ht0, tw1t, tb1, ht1, 1024, 1024, 1);
    gemm_bt<<<dim3(512 / 128,  M_BATCH / 128), blk, 0, stream>>>(ht1, tw2t, tb2, ht2, 512, 1024, 1);
    gemm_bt<<<dim3(256 / 128,  M_BATCH / 128), blk, 0, stream>>>(ht2, tw3t, tb3, ht3, 256, 512, 1);
    top_final<<<dim3(M_BATCH / 4), blk, 0, stream>>>(ht3, tw4, tb4, out);
}